// Round 4
// baseline (620.983 us; speedup 1.0000x reference)
//
#include <hip/hip_runtime.h>
#include <stdint.h>

// Problem constants (B,H,W,C)=(2,192,192,192), WS=16, SHIFT=8, NH=6
#define HH 192
#define WWW 192
#define CC 192
#define WS 16
#define SHIFTS 8
#define NH 6
#define HD 32
#define NN 256
#define NWS 12
#define NWIN_B 144
#define NWIN 288
#define CTN (NWIN * NN)          // 73728 floats per ct table

typedef _Float16 half_t;
typedef half_t half2_t __attribute__((ext_vector_type(2)));

// saturating f32->f16 pack: launders NaN (fminf/fmaxf drop NaN operand) and caps inf
__device__ __forceinline__ float sat16(float a) {
    return fminf(fmaxf(a, -60000.f), 60000.f);
}
__device__ __forceinline__ uint32_t pack_h2(float a, float b) {
    half2_t h; h.x = (half_t)sat16(a); h.y = (half_t)sat16(b);
    return __builtin_bit_cast(uint32_t, h);
}

#if __has_builtin(__builtin_amdgcn_fdot2)
__device__ __forceinline__ float fdot2u(uint32_t a, uint32_t b, float c) {
    return __builtin_amdgcn_fdot2(__builtin_bit_cast(half2_t, a),
                                  __builtin_bit_cast(half2_t, b), c, false);
}
#else
__device__ __forceinline__ float fdot2u(uint32_t a, uint32_t b, float c) {
    half2_t ha = __builtin_bit_cast(half2_t, a);
    half2_t hb = __builtin_bit_cast(half2_t, b);
    return c + (float)ha.x * (float)hb.x + (float)ha.y * (float)hb.y;
}
#endif

// post-shift (sh,sw) -> original coords (roll by -SHIFT: s[i] = x[(i+SHIFT)%N])
__device__ __forceinline__ size_t xrow(int b, int sh, int sw) {
    int oh = sh + SHIFTS; if (oh >= HH) oh -= HH;
    int ow = sw + SHIFTS; if (ow >= WWW) ow -= WWW;
    return ((size_t)((b * HH + oh) * WWW + ow)) * CC;
}
__device__ __forceinline__ size_t qkvrow(int b, int sh, int sw) {
    int oh = sh + SHIFTS; if (oh >= HH) oh -= HH;
    int ow = sw + SHIFTS; if (ow >= WWW) ow -= WWW;
    return ((size_t)((b * HH + oh) * WWW + ow)) * (3 * CC);
}
// shift-mask region id along one axis (post-shift / mask-image coordinates)
__device__ __forceinline__ int regof(int v) { return v < (HH - WS) ? 0 : (v < (HH - SHIFTS) ? 1 : 2); }

// ct tables parked in SECOND halves (floats [96,192)) of d_out row-slots 0..3071.
// flat index q in [0, 2*CTN) -> float position in d_out.
__device__ __forceinline__ float* ctptr(float* o, int q) {
    int slot = q / 96;            // magic-mul, constant divisor
    int off = q - slot * 96;
    return o + (size_t)slot * CC + 96 + off;
}

// ---------------- Kernel A: geo cumsum tables (once per window) ----------------
__global__ __launch_bounds__(256) void kgeo(const float* __restrict__ x,
                                            const float* __restrict__ sigp,
                                            float* __restrict__ outbuf) {
    __shared__ float dh[16][16];
    __shared__ float dv[16][16];
    int win = blockIdx.x;
    int b = win / NWIN_B, wi = win % NWIN_B;
    int wr = wi / NWS, wc = wi % NWS;
    int t = threadIdx.x;
    int r = t >> 4, j = t & 15;
    int r1 = (r < 15) ? r + 1 : r;
    int j1 = (j < 15) ? j + 1 : j;

    const float4* a4 = (const float4*)(x + xrow(b, wr * WS + r,  wc * WS + j));
    const float4* b4 = (const float4*)(x + xrow(b, wr * WS + r,  wc * WS + j1));
    const float4* c4 = (const float4*)(x + xrow(b, wr * WS + r1, wc * WS + j));
    float sh_ = 0.f, sv_ = 0.f;
    #pragma unroll 4
    for (int ch = 0; ch < 48; ch++) {
        float4 fa = a4[ch], fb = b4[ch], fc = c4[ch];
        sh_ += fabsf(fb.x - fa.x) + fabsf(fb.y - fa.y) + fabsf(fb.z - fa.z) + fabsf(fb.w - fa.w);
        sv_ += fabsf(fc.x - fa.x) + fabsf(fc.y - fa.y) + fabsf(fc.z - fa.z) + fabsf(fc.w - fa.w);
    }
    dh[r][j] = (j < 15) ? sh_ : 0.f;
    dv[r][j] = (r < 15) ? sv_ : 0.f;
    __syncthreads();

    float sigma = fabsf(sigp[0]);
    if (t < 16) {
        float acc = 0.f;
        *ctptr(outbuf, win * NN + t * 16) = 0.f;
        for (int jj = 1; jj < 16; jj++) {
            acc += 1.0f + sigma * dh[t][jj - 1];
            *ctptr(outbuf, win * NN + t * 16 + jj) = acc;
        }
    } else if (t < 32) {
        int c = t - 16;
        float acc = 0.f;
        *ctptr(outbuf, CTN + win * NN + c) = 0.f;
        for (int ii = 1; ii < 16; ii++) {
            acc += 1.0f + sigma * dv[ii - 1][c];
            *ctptr(outbuf, CTN + win * NN + ii * 16 + c) = acc;
        }
    }
}

// ------- Kernel B: windowed attention; f16 att -> first half of own d_out row-slot -------
__global__ __launch_bounds__(256) void kattn(const float* __restrict__ qkv,
                                             const float* __restrict__ rpb_table,
                                             const float* __restrict__ geo_scale,
                                             float* __restrict__ outbuf) {
    __shared__ uint32_t Kpk[256][20];   // [k][d-pair]
    __shared__ uint32_t Vpk[128][36];   // [k-pair][d]
    __shared__ float cth_s[NN], ctv_s[NN];
    __shared__ float rpb_s[961];

    int win = blockIdx.x, head = blockIdx.y;
    int b = win / NWIN_B, wi = win % NWIN_B;
    int wr = wi / NWS, wc = wi % NWS;
    int t = threadIdx.x;
    int rr = t >> 4, pc = t & 15;

    cth_s[t] = *ctptr(outbuf, win * NN + t);
    ctv_s[t] = *ctptr(outbuf, CTN + win * NN + t);
    for (int i = t; i < 961; i += 256) rpb_s[i] = rpb_table[i * NH + head];

    size_t rowb = qkvrow(b, wr * WS + rr, wc * WS + pc);
    // K row t -> LDS (channel pairs as half2)
    {
        const float4* k4 = (const float4*)(qkv + rowb + CC + head * HD);
        #pragma unroll
        for (int c4 = 0; c4 < 8; c4++) {
            float4 u = k4[c4];
            Kpk[t][c4 * 2 + 0] = pack_h2(u.x, u.y);
            Kpk[t][c4 * 2 + 1] = pack_h2(u.z, u.w);
        }
    }
    // V pair rows (2t,2t+1) -> LDS transposed-by-pairs: Vpk[kk][d] = (V[2kk][d], V[2kk+1][d])
    if (t < 128) {
        int p0 = 2 * t, p1 = 2 * t + 1;
        const float4* v0 = (const float4*)(qkv + qkvrow(b, wr * WS + (p0 >> 4), wc * WS + (p0 & 15)) + 2 * CC + head * HD);
        const float4* v1 = (const float4*)(qkv + qkvrow(b, wr * WS + (p1 >> 4), wc * WS + (p1 & 15)) + 2 * CC + head * HD);
        #pragma unroll
        for (int c4 = 0; c4 < 8; c4++) {
            float4 a = v0[c4], bu = v1[c4];
            Vpk[t][c4 * 4 + 0] = pack_h2(a.x, bu.x);
            Vpk[t][c4 * 4 + 1] = pack_h2(a.y, bu.y);
            Vpk[t][c4 * 4 + 2] = pack_h2(a.z, bu.z);
            Vpk[t][c4 * 4 + 3] = pack_h2(a.w, bu.w);
        }
    }
    // Q row t -> registers (channel pairs as half2)
    uint32_t qv[16];
    {
        const float4* q4 = (const float4*)(qkv + rowb + head * HD);
        #pragma unroll
        for (int c4 = 0; c4 < 8; c4++) {
            float4 u = q4[c4];
            qv[c4 * 2 + 0] = pack_h2(u.x, u.y);
            qv[c4 * 2 + 1] = pack_h2(u.z, u.w);
        }
    }
    __syncthreads();

    int rq = rr, cq = pc;
    int rq16 = rq * 16;
    float ghq = cth_s[t];
    int qb = rq * 31 + cq + 480;   // rpi(q,k) = qb - (rk*31+ck)
    int regq = 3 * regof(wr * WS + rq) + regof(wc * WS + cq);
    float gscale = geo_scale[head];
    const float scale = 0.17677669529663687f;  // 32^-0.5

    float m = -INFINITY, l = 0.f;
    float o[32];
    #pragma unroll
    for (int d = 0; d < 32; d++) o[d] = 0.f;

    #pragma unroll 2
    for (int kk = 0; kk < 128; kk++) {
        int k0 = kk * 2, k1 = k0 + 1;
        const uint4* kr0 = (const uint4*)&Kpk[k0][0];
        const uint4* kr1 = (const uint4*)&Kpk[k1][0];
        uint4 A0 = kr0[0], A1 = kr0[1], A2 = kr0[2], A3 = kr0[3];
        uint4 B0 = kr1[0], B1 = kr1[1], B2 = kr1[2], B3 = kr1[3];

        float s0a = 0.f, s0b = 0.f, s0c = 0.f, s0d = 0.f;
        float s1a = 0.f, s1b = 0.f, s1c = 0.f, s1d = 0.f;
        s0a = fdot2u(qv[0],  A0.x, s0a); s0b = fdot2u(qv[1],  A0.y, s0b);
        s0c = fdot2u(qv[2],  A0.z, s0c); s0d = fdot2u(qv[3],  A0.w, s0d);
        s0a = fdot2u(qv[4],  A1.x, s0a); s0b = fdot2u(qv[5],  A1.y, s0b);
        s0c = fdot2u(qv[6],  A1.z, s0c); s0d = fdot2u(qv[7],  A1.w, s0d);
        s0a = fdot2u(qv[8],  A2.x, s0a); s0b = fdot2u(qv[9],  A2.y, s0b);
        s0c = fdot2u(qv[10], A2.z, s0c); s0d = fdot2u(qv[11], A2.w, s0d);
        s0a = fdot2u(qv[12], A3.x, s0a); s0b = fdot2u(qv[13], A3.y, s0b);
        s0c = fdot2u(qv[14], A3.z, s0c); s0d = fdot2u(qv[15], A3.w, s0d);
        s1a = fdot2u(qv[0],  B0.x, s1a); s1b = fdot2u(qv[1],  B0.y, s1b);
        s1c = fdot2u(qv[2],  B0.z, s1c); s1d = fdot2u(qv[3],  B0.w, s1d);
        s1a = fdot2u(qv[4],  B1.x, s1a); s1b = fdot2u(qv[5],  B1.y, s1b);
        s1c = fdot2u(qv[6],  B1.z, s1c); s1d = fdot2u(qv[7],  B1.w, s1d);
        s1a = fdot2u(qv[8],  B2.x, s1a); s1b = fdot2u(qv[9],  B2.y, s1b);
        s1c = fdot2u(qv[10], B2.z, s1c); s1d = fdot2u(qv[11], B2.w, s1d);
        s1a = fdot2u(qv[12], B3.x, s1a); s1b = fdot2u(qv[13], B3.y, s1b);
        s1c = fdot2u(qv[14], B3.z, s1c); s1d = fdot2u(qv[15], B3.w, s1d);
        float s0 = (s0a + s0b) + (s0c + s0d);
        float s1 = (s1a + s1b) + (s1c + s1d);

        int rk0 = k0 >> 4, ck0 = k0 & 15;
        int rk1 = k1 >> 4, ck1 = k1 & 15;
        float rpb0 = rpb_s[qb - (rk0 * 31 + ck0)];
        float rpb1 = rpb_s[qb - (rk1 * 31 + ck1)];
        float geo0 = fabsf(cth_s[rq16 + ck0] - ghq) + fabsf(ctv_s[k0] - ctv_s[rq16 + ck0]);
        float geo1 = fabsf(cth_s[rq16 + ck1] - ghq) + fabsf(ctv_s[k1] - ctv_s[rq16 + ck1]);
        int regk0 = 3 * regof(wr * WS + rk0) + regof(wc * WS + ck0);
        int regk1 = 3 * regof(wr * WS + rk1) + regof(wc * WS + ck1);
        float sm0 = (regk0 == regq) ? 0.f : -100.f;
        float sm1 = (regk1 == regq) ? 0.f : -100.f;
        s0 = s0 * scale + rpb0 - gscale * geo0 + sm0;
        s1 = s1 * scale + rpb1 - gscale * geo1 + sm1;
        // NaN/inf laundering safety net (no-op on clean data)
        s0 = fminf(fmaxf(s0, -3.0e38f), 3.0e38f);
        s1 = fminf(fmaxf(s1, -3.0e38f), 3.0e38f);

        float mn = fmaxf(m, fmaxf(s0, s1));
        if (mn > m) {
            float corr = __expf(m - mn);
            l *= corr;
            #pragma unroll
            for (int d = 0; d < 32; d++) o[d] *= corr;
            m = mn;
        }
        float p0 = __expf(s0 - m), p1 = __expf(s1 - m);
        l += p0 + p1;
        uint32_t pp = pack_h2(p0, p1);

        const uint4* vr = (const uint4*)&Vpk[kk][0];
        #pragma unroll
        for (int c4 = 0; c4 < 8; c4++) {
            uint4 v = vr[c4];
            o[c4 * 4 + 0] = fdot2u(pp, v.x, o[c4 * 4 + 0]);
            o[c4 * 4 + 1] = fdot2u(pp, v.y, o[c4 * 4 + 1]);
            o[c4 * 4 + 2] = fdot2u(pp, v.z, o[c4 * 4 + 2]);
            o[c4 * 4 + 3] = fdot2u(pp, v.w, o[c4 * 4 + 3]);
        }
    }

    float inv = 1.0f / l;
    // final spatial row (window reverse + roll(+SHIFT))
    int oh = wr * WS + rr + SHIFTS; if (oh >= HH) oh -= HH;
    int ow = wc * WS + pc + SHIFTS; if (ow >= WWW) ow -= WWW;
    size_t R = (size_t)b * (HH * WWW) + oh * WWW + ow;
    // f16 att staged in FIRST 384 B of row R's own 768 B f32 slot
    uint4* o4p = (uint4*)outbuf;
    size_t base4 = R * 48 + head * 4;
    #pragma unroll
    for (int g = 0; g < 4; g++) {
        uint4 st;
        st.x = pack_h2(o[g * 8 + 0] * inv, o[g * 8 + 1] * inv);
        st.y = pack_h2(o[g * 8 + 2] * inv, o[g * 8 + 3] * inv);
        st.z = pack_h2(o[g * 8 + 4] * inv, o[g * 8 + 5] * inv);
        st.w = pack_h2(o[g * 8 + 6] * inv, o[g * 8 + 7] * inv);
        o4p[base4 + g] = st;
    }
}

// ------- Kernel C: in-place projection GEMM on d_out (f16 in slot-half, f32 out full slot) -------
// Block owns rows [R0, R0+64): read-set (first halves) subset of write-set -> race-free.
__global__ __launch_bounds__(256) void kproj(float* __restrict__ data,
                                             const float* __restrict__ proj_w,
                                             const float* __restrict__ proj_b) {
    __shared__ uint32_t Apk[64][100];   // [row][c-pair], +4 pad
    __shared__ uint32_t Wl[16][196];    // [c-pair-in-chunk][j], +4 pad
    size_t R0 = (size_t)blockIdx.x * 64;
    int t = threadIdx.x;

    // stage A tile: 64 rows x 24 uint4 (f16 att), slot stride 48 uint4
    const uint4* in4 = (const uint4*)data + R0 * 48;
    #pragma unroll
    for (int i = 0; i < 6; i++) {
        int idx = t + i * 256;          // < 1536
        int r = idx / 24, q = idx % 24;
        uint4 u = in4[(size_t)r * 48 + q];
        Apk[r][q * 4 + 0] = u.x; Apk[r][q * 4 + 1] = u.y;
        Apk[r][q * 4 + 2] = u.z; Apk[r][q * 4 + 3] = u.w;
    }

    int rq = t >> 4, jg = t & 15;
    int r0 = rq * 4, j0 = jg * 12;
    float acc[48];
    #pragma unroll
    for (int i = 0; i < 48; i++) acc[i] = 0.f;

    const float2* pw2 = (const float2*)proj_w;   // pairs of channels per row j
    for (int ch = 0; ch < 6; ch++) {
        __syncthreads();   // A ready (ch=0) / previous Wl fully consumed
        #pragma unroll
        for (int i = 0; i < 12; i++) {
            int idx = t + i * 256;      // < 3072
            int j = idx >> 4, ccl = idx & 15;
            float2 f = pw2[j * 96 + ch * 16 + ccl];  // W[j][2cc], W[j][2cc+1]
            Wl[ccl][j] = pack_h2(f.x, f.y);
        }
        __syncthreads();
        #pragma unroll
        for (int ccl = 0; ccl < 16; ccl++) {
            int cc = ch * 16 + ccl;
            uint32_t a0 = Apk[r0 + 0][cc];
            uint32_t a1 = Apk[r0 + 1][cc];
            uint32_t a2 = Apk[r0 + 2][cc];
            uint32_t a3 = Apk[r0 + 3][cc];
            const uint4* wp = (const uint4*)&Wl[ccl][j0];
            uint4 w0 = wp[0], w1 = wp[1], w2 = wp[2];
            acc[0]  = fdot2u(a0, w0.x, acc[0]);  acc[1]  = fdot2u(a0, w0.y, acc[1]);
            acc[2]  = fdot2u(a0, w0.z, acc[2]);  acc[3]  = fdot2u(a0, w0.w, acc[3]);
            acc[4]  = fdot2u(a0, w1.x, acc[4]);  acc[5]  = fdot2u(a0, w1.y, acc[5]);
            acc[6]  = fdot2u(a0, w1.z, acc[6]);  acc[7]  = fdot2u(a0, w1.w, acc[7]);
            acc[8]  = fdot2u(a0, w2.x, acc[8]);  acc[9]  = fdot2u(a0, w2.y, acc[9]);
            acc[10] = fdot2u(a0, w2.z, acc[10]); acc[11] = fdot2u(a0, w2.w, acc[11]);
            acc[12] = fdot2u(a1, w0.x, acc[12]); acc[13] = fdot2u(a1, w0.y, acc[13]);
            acc[14] = fdot2u(a1, w0.z, acc[14]); acc[15] = fdot2u(a1, w0.w, acc[15]);
            acc[16] = fdot2u(a1, w1.x, acc[16]); acc[17] = fdot2u(a1, w1.y, acc[17]);
            acc[18] = fdot2u(a1, w1.z, acc[18]); acc[19] = fdot2u(a1, w1.w, acc[19]);
            acc[20] = fdot2u(a1, w2.x, acc[20]); acc[21] = fdot2u(a1, w2.y, acc[21]);
            acc[22] = fdot2u(a1, w2.z, acc[22]); acc[23] = fdot2u(a1, w2.w, acc[23]);
            acc[24] = fdot2u(a2, w0.x, acc[24]); acc[25] = fdot2u(a2, w0.y, acc[25]);
            acc[26] = fdot2u(a2, w0.z, acc[26]); acc[27] = fdot2u(a2, w0.w, acc[27]);
            acc[28] = fdot2u(a2, w1.x, acc[28]); acc[29] = fdot2u(a2, w1.y, acc[29]);
            acc[30] = fdot2u(a2, w1.z, acc[30]); acc[31] = fdot2u(a2, w1.w, acc[31]);
            acc[32] = fdot2u(a2, w2.x, acc[32]); acc[33] = fdot2u(a2, w2.y, acc[33]);
            acc[34] = fdot2u(a2, w2.z, acc[34]); acc[35] = fdot2u(a2, w2.w, acc[35]);
            acc[36] = fdot2u(a3, w0.x, acc[36]); acc[37] = fdot2u(a3, w0.y, acc[37]);
            acc[38] = fdot2u(a3, w0.z, acc[38]); acc[39] = fdot2u(a3, w0.w, acc[39]);
            acc[40] = fdot2u(a3, w1.x, acc[40]); acc[41] = fdot2u(a3, w1.y, acc[41]);
            acc[42] = fdot2u(a3, w1.z, acc[42]); acc[43] = fdot2u(a3, w1.w, acc[43]);
            acc[44] = fdot2u(a3, w2.x, acc[44]); acc[45] = fdot2u(a3, w2.y, acc[45]);
            acc[46] = fdot2u(a3, w2.z, acc[46]); acc[47] = fdot2u(a3, w2.w, acc[47]);
        }
    }

    // bias + f32 store back to the SAME rows (16B-aligned float4 stores)
    float bv[12];
    #pragma unroll
    for (int jj = 0; jj < 12; jj++) bv[jj] = proj_b[j0 + jj];
    #pragma unroll
    for (int rr2 = 0; rr2 < 4; rr2++) {
        size_t R = R0 + r0 + rr2;
        float4* st4 = (float4*)(data + R * CC + j0);
        const float* a = &acc[rr2 * 12];
        st4[0] = make_float4(a[0] + bv[0],  a[1] + bv[1],  a[2]  + bv[2],  a[3]  + bv[3]);
        st4[1] = make_float4(a[4] + bv[4],  a[5] + bv[5],  a[6]  + bv[6],  a[7]  + bv[7]);
        st4[2] = make_float4(a[8] + bv[8],  a[9] + bv[9],  a[10] + bv[10], a[11] + bv[11]);
    }
}

extern "C" void kernel_launch(void* const* d_in, const int* in_sizes, int n_in,
                              void* d_out, int out_size, void* d_ws, size_t ws_size,
                              hipStream_t stream) {
    // Resolve float32 inputs by unique element count (belt-and-braces vs dict order)
    const float *x = nullptr, *qkv = nullptr, *rpb = nullptr, *gsc = nullptr,
                *pw = nullptr, *pb = nullptr, *sig = nullptr;
    for (int i = 0; i < n_in; i++) {
        switch (in_sizes[i]) {
            case 14155776: x   = (const float*)d_in[i]; break;  // 2*192*192*192
            case 42467328: qkv = (const float*)d_in[i]; break;  // 3x
            case 5766:     rpb = (const float*)d_in[i]; break;  // 961*6
            case 6:        gsc = (const float*)d_in[i]; break;  // NH
            case 36864:    pw  = (const float*)d_in[i]; break;  // 192*192
            case 192:      pb  = (const float*)d_in[i]; break;
            default: break;  // rpi(65536), attn_mask(589824), scalars
        }
    }
    // geo_sigma: first size-1 input in dict order (index 4 per setup_inputs)
    if (n_in > 4 && in_sizes[4] == 1) sig = (const float*)d_in[4];
    else for (int i = 0; i < n_in; i++) if (in_sizes[i] == 1) { sig = (const float*)d_in[i]; break; }
    // fallback to dict order if anything unresolved
    if (!x)   x   = (const float*)d_in[0];
    if (!qkv) qkv = (const float*)d_in[1];
    if (!rpb) rpb = (const float*)d_in[2];
    if (!gsc) gsc = (const float*)d_in[3];
    if (!sig) sig = (const float*)d_in[4];
    if (!pw)  pw  = (const float*)d_in[5];
    if (!pb)  pb  = (const float*)d_in[6];

    float* out = (float*)d_out;   // reference output dtype: float32
    // d_ws unused: ct tables live in second halves of d_out row-slots 0..3071;
    // f16 att lives in the first half of each row's own f32 slot (in-place kproj).

    kgeo<<<dim3(NWIN), dim3(256), 0, stream>>>(x, sig, out);
    kattn<<<dim3(NWIN, NH), dim3(256), 0, stream>>>(qkv, rpb, gsc, out);
    kproj<<<dim3((NWIN * NN) / 64), dim3(256), 0, stream>>>(out, pw, pb);
}